// Round 7
// baseline (140.162 us; speedup 1.0000x reference)
//
#include <hip/hip_runtime.h>
#include <cstdint>
#include <cstddef>

#define THETA 1.2f
#define XI 0.3f
#define BDIM 8192
#define DDIM 512
#define NTILE 64           // 64x64 grid of 128x128 tiles
#define NUPPER 2080        // NTILE*(NTILE+1)/2 upper-triangle block-tiles
#define GRID 512           // 2 blocks/CU x 256 CU: all resident at t=0, balanced
// upper-triangle-with-diagonal pair count: B*(B+1)/2
#define NPAIRS_UP (((double)BDIM * (double)(BDIM + 1)) * 0.5)

typedef float f32x4 __attribute__((ext_vector_type(4)));
typedef int i32x8 __attribute__((ext_vector_type(8)));

// ---------------------------------------------------------------------------
// Fragment-major ("tiled") fp8 layout (verified r6):
//   frag F = (row/16)*4 + (kbyte/128)   -- 16 rows x 128 B of K = one MFMA frag
//   blob of 2048 B at F*2048; lane l holds its 32 B at offset l*32 -- exactly
//   the mfma_scale 16x16x128 operand order. Frag load = contiguous 2 KB/wave.
// ---------------------------------------------------------------------------

// Kernel 1: per-row L2 normalize fp32 -> fp8 e4m3 into tiled layout;
// sq[row]=||n||^2; zero counter.
__global__ __launch_bounds__(256) void normalize_rows(
    const float* __restrict__ x, unsigned char* __restrict__ nf8,
    float* __restrict__ sq, unsigned int* __restrict__ counter)
{
    if (blockIdx.x == 0 && threadIdx.x == 0) { *counter = 0u; }
    int row = blockIdx.x * 4 + (threadIdx.x >> 6);
    int l = threadIdx.x & 63;
    const float4* xr = (const float4*)(x + (size_t)row * DDIM);
    float4 f0 = xr[l];
    float4 f1 = xr[l + 64];
    float s = f0.x*f0.x + f0.y*f0.y + f0.z*f0.z + f0.w*f0.w
            + f1.x*f1.x + f1.y*f1.y + f1.z*f1.z + f1.w*f1.w;
    #pragma unroll
    for (int m = 1; m < 64; m <<= 1) s += __shfl_xor(s, m);
    float rn = rsqrtf(s);
    int pk0 = __builtin_amdgcn_cvt_pk_fp8_f32(f0.x * rn, f0.y * rn, 0, false);
    pk0     = __builtin_amdgcn_cvt_pk_fp8_f32(f0.z * rn, f0.w * rn, pk0, true);
    int pk1 = __builtin_amdgcn_cvt_pk_fp8_f32(f1.x * rn, f1.y * rn, 0, false);
    pk1     = __builtin_amdgcn_cvt_pk_fp8_f32(f1.z * rn, f1.w * rn, pk1, true);
    // tiled scatter: pk0 covers k=[4l,4l+4), pk1 covers k=[4l+256,4l+260)
    size_t base = (size_t)(row >> 4) * 4 * 2048;
    int within = ((row & 15) + ((l >> 3) & 3) * 16) * 32 + (l & 7) * 4;
    int kc0 = l >> 5;          // k=4l       -> kc in {0,1}
    int kc1 = (l >> 5) + 2;    // k=4l+256   -> kc in {2,3}
    *(int*)(nf8 + base + (size_t)kc0 * 2048 + within) = pk0;
    *(int*)(nf8 + base + (size_t)kc1 * 2048 + within) = pk1;
    if (l == 0) sq[row] = s * rn * rn;
}

__device__ __forceinline__ void decode_tile(int u, int& ti, int& tj) {
    // u = tj*(tj+1)/2 + ti, ti <= tj
    int t = (int)((sqrtf(8.0f * (float)u + 1.0f) - 1.0f) * 0.5f);
    while ((t + 1) * (t + 2) / 2 <= u) ++t;
    while (t * (t + 1) / 2 > u) --t;
    tj = t;
    ti = u - t * (t + 1) / 2;
}

// Kernel 2: NO LDS staging, NO barriers in the compute path. 4 waves = 2x2
// quadrants of a 128x128 tile (each 2 KB frag read by 2 waves -> L1 catches
// the pair's second read). Depth-1 register software pipeline: chunk c+1's
// 16 operand loads (af[4]+bf[4], contiguous 2 KB each) are issued BEFORE
// chunk c's MFMAs; the compiler's dependence-tracked counted vmcnt leaves
// them outstanding while chunk c computes. Even/odd statically-named double
// buffers inside an unroll-1 loop (r1's full unroll exploded registers;
// runtime-indexed buffers would go to scratch). sched_barrier(0) pins the
// loop-body shape. VGPR: 64 acc + 128 dbuf + ~20 addr ~= 210 -> (256,2),
// no spill by construction.
__global__ __launch_bounds__(256, 2) void gram_hinge(
    const unsigned char* __restrict__ nf8, const float* __restrict__ sq,
    const int* __restrict__ y, double* __restrict__ part,
    unsigned int* __restrict__ counter, float* __restrict__ out)
{
    __shared__ float wpart[4];
    __shared__ double dpart[4];
    __shared__ int is_last;

    int tid = threadIdx.x;
    int w = tid >> 6, l = tid & 63;
    int wr = w >> 1, wc = w & 1;      // wave quadrant in 128x128 tile
    int lr = l & 15, q = l >> 4;

    float acc0 = 0.f, acc1 = 0.f, acc2 = 0.f, acc3 = 0.f;

    int u = blockIdx.x;
    int ti, tj;
    decode_tile(u, ti, tj);

    while (u < NUPPER) {
        // per-lane frag base pointers for this tile's quadrant
        const unsigned char* pA = nf8 + ((size_t)((ti * 8 + wr * 4) * 4)) * 2048 + l * 32;
        const unsigned char* pB = nf8 + ((size_t)((tj * 8 + wc * 4) * 4)) * 2048 + l * 32;
        // frag (f, chunk c) at p + f*8192 + c*2048

        f32x4 accv[4][4] = {};
        i32x8 afe[4], bfe[4], afo[4], bfo[4];

        // prologue: chunk 0 -> even buffers (16 loads)
        #pragma unroll
        for (int f = 0; f < 4; ++f) {
            afe[f] = *(const i32x8*)(pA + f * 8192);
            bfe[f] = *(const i32x8*)(pB + f * 8192);
        }

        #pragma unroll 1
        for (int cc = 0; cc < 2; ++cc) {
            int codd = cc * 2 + 1;                 // 1, 3
            // issue odd-chunk loads (stay outstanding through even MFMAs)
            #pragma unroll
            for (int f = 0; f < 4; ++f) {
                afo[f] = *(const i32x8*)(pA + f * 8192 + codd * 2048);
                bfo[f] = *(const i32x8*)(pB + f * 8192 + codd * 2048);
            }
            __builtin_amdgcn_sched_barrier(0);
            // compute even chunk 2cc (waits even regs; odd loads in flight)
            __builtin_amdgcn_s_setprio(1);
            #pragma unroll
            for (int mi = 0; mi < 4; ++mi)
                #pragma unroll
                for (int ni = 0; ni < 4; ++ni)
                    accv[mi][ni] = __builtin_amdgcn_mfma_scale_f32_16x16x128_f8f6f4(
                        afe[mi], bfe[ni], accv[mi][ni],
                        0, 0, 0, 0x7F7F7F7F, 0, 0x7F7F7F7F);
            __builtin_amdgcn_s_setprio(0);
            __builtin_amdgcn_sched_barrier(0);
            // issue next even chunk (c=2) loads -- only mid-tile
            if (cc == 0) {
                #pragma unroll
                for (int f = 0; f < 4; ++f) {
                    afe[f] = *(const i32x8*)(pA + f * 8192 + 2 * 2048);
                    bfe[f] = *(const i32x8*)(pB + f * 8192 + 2 * 2048);
                }
            }
            __builtin_amdgcn_sched_barrier(0);
            // compute odd chunk (waits odd regs; even loads in flight)
            __builtin_amdgcn_s_setprio(1);
            #pragma unroll
            for (int mi = 0; mi < 4; ++mi)
                #pragma unroll
                for (int ni = 0; ni < 4; ++ni)
                    accv[mi][ni] = __builtin_amdgcn_mfma_scale_f32_16x16x128_f8f6f4(
                        afo[mi], bfo[ni], accv[mi][ni],
                        0, 0, 0, 0x7F7F7F7F, 0, 0x7F7F7F7F);
            __builtin_amdgcn_s_setprio(0);
            __builtin_amdgcn_sched_barrier(0);
        }

        // ---- per-tile epilogue (C/D layout: col=lane&15 -> j, row=q*4+reg -> i) ----
        {
            int jb = tj * 128 + wc * 64 + lr;
            float sqj[4]; int yj[4];
            #pragma unroll
            for (int ni = 0; ni < 4; ++ni) {
                sqj[ni] = sq[jb + ni * 16];
                yj[ni]  = y[jb + ni * 16];
            }
            bool skip = (ti == tj) && (wr > wc);        // strictly below diag
            bool full = (ti != tj) || (wc > wr);        // fully above diag
            if (!skip) {
                if (full) {
                    #pragma unroll
                    for (int mi = 0; mi < 4; ++mi) {
                        #pragma unroll
                        for (int r = 0; r < 4; ++r) {
                            int ia = ti * 128 + wr * 64 + mi * 16 + q * 4 + r;
                            float ci = THETA - sq[ia];
                            int yi = y[ia];
                            float h0 = fmaxf(fmaf(2.f, accv[mi][0][r], ci - sqj[0]), 0.f);
                            acc0 += (yi == yj[0]) ? h0 : -h0;
                            float h1 = fmaxf(fmaf(2.f, accv[mi][1][r], ci - sqj[1]), 0.f);
                            acc1 += (yi == yj[1]) ? h1 : -h1;
                            float h2 = fmaxf(fmaf(2.f, accv[mi][2][r], ci - sqj[2]), 0.f);
                            acc2 += (yi == yj[2]) ? h2 : -h2;
                            float h3 = fmaxf(fmaf(2.f, accv[mi][3][r], ci - sqj[3]), 0.f);
                            acc3 += (yi == yj[3]) ? h3 : -h3;
                        }
                    }
                } else {
                    // diagonal quadrant (wr==wc): count local col >= local row
                    #pragma unroll
                    for (int mi = 0; mi < 4; ++mi) {
                        #pragma unroll
                        for (int r = 0; r < 4; ++r) {
                            int rl_ = mi * 16 + q * 4 + r;
                            int ia = ti * 128 + wr * 64 + rl_;
                            float ci = THETA - sq[ia];
                            int yi = y[ia];
                            #pragma unroll
                            for (int ni = 0; ni < 4; ++ni) {
                                float h = fmaxf(fmaf(2.f, accv[mi][ni][r], ci - sqj[ni]), 0.f);
                                float sh = (yi == yj[ni]) ? h : -h;
                                if (ni * 16 + lr >= rl_) acc0 += sh;
                            }
                        }
                    }
                }
            }
        }

        u += GRID;
        if (u < NUPPER) decode_tile(u, ti, tj);
    }

    float local = (acc0 + acc1) + (acc2 + acc3);
    #pragma unroll
    for (int off = 32; off > 0; off >>= 1) local += __shfl_down(local, off);
    if (l == 0) wpart[w] = local;
    __syncthreads();
    if (tid == 0) {
        double ssum = (double)wpart[0] + (double)wpart[1]
                    + (double)wpart[2] + (double)wpart[3];
        __hip_atomic_store(&part[blockIdx.x], ssum, __ATOMIC_RELEASE, __HIP_MEMORY_SCOPE_AGENT);
        unsigned int ticket = __hip_atomic_fetch_add(
            counter, 1u, __ATOMIC_ACQ_REL, __HIP_MEMORY_SCOPE_AGENT);
        is_last = (ticket == GRID - 1) ? 1 : 0;
    }
    __syncthreads();
    if (is_last) {
        double s = 0.0;
        for (int i = tid; i < GRID; i += 256)
            s += __hip_atomic_load(&part[i], __ATOMIC_ACQUIRE, __HIP_MEMORY_SCOPE_AGENT);
        #pragma unroll
        for (int off = 32; off > 0; off >>= 1) s += __shfl_down(s, off);
        if (l == 0) dpart[w] = s;
        __syncthreads();
        if (tid == 0) {
            // add the analytically-known XI term: XI * #upper-tri pairs
            double total = (dpart[0] + dpart[1] + dpart[2] + dpart[3])
                         + (double)XI * NPAIRS_UP;
            const double m = 1.0 / ((double)BDIM * (double)BDIM - (double)BDIM);
            out[0] = (float)(total * m);
        }
    }
}

extern "C" void kernel_launch(void* const* d_in, const int* in_sizes, int n_in,
                              void* d_out, int out_size, void* d_ws, size_t ws_size,
                              hipStream_t stream) {
    const float* x = (const float*)d_in[0];
    const int* y = (const int*)d_in[1];
    float* out = (float*)d_out;

    unsigned char* nf8 = (unsigned char*)d_ws;                          // 4 MB fp8 (tiled)
    char* p = (char*)d_ws + (size_t)BDIM * DDIM;
    float* sq = (float*)p;                                              // 32 KB
    unsigned int* counter = (unsigned int*)(p + (size_t)BDIM * 4);
    double* part = (double*)(p + (size_t)BDIM * 4 + 64);                // GRID doubles

    normalize_rows<<<BDIM / 4, 256, 0, stream>>>(x, nf8, sq, counter);
    gram_hinge<<<GRID, 256, 0, stream>>>(nf8, sq, y, part, counter, out);
}

// Round 8
// 108.124 us; speedup vs baseline: 1.2963x; 1.2963x over previous
//
#include <hip/hip_runtime.h>
#include <cstdint>
#include <cstddef>

#define THETA 1.2f
#define XI 0.3f
#define BDIM 8192
#define DDIM 512
#define NTILE 64           // 64x64 grid of 128x128 tiles
#define NUPPER 2080        // NTILE*(NTILE+1)/2 upper-triangle block-tiles
#define GRID 512           // 2 blocks/CU x 256 CU: ALL resident at t=0, no straggler round
// upper-triangle-with-diagonal pair count: B*(B+1)/2
#define NPAIRS_UP (((double)BDIM * (double)(BDIM + 1)) * 0.5)

typedef float f32x4 __attribute__((ext_vector_type(4)));
typedef int i32x8 __attribute__((ext_vector_type(8)));

// ---------------------------------------------------------------------------
// Fragment-major ("tiled") fp8 layout (verified r6/r7):
//   frag F = (row/16)*4 + (kbyte/128)   -- 16 rows x 128 B of K = one MFMA frag
//   blob of 2048 B at F*2048; lane l holds its 32 B at offset l*32 -- exactly
//   the mfma_scale 16x16x128 operand order. Frag load = contiguous 2 KB/wave.
// ---------------------------------------------------------------------------

// Kernel 1: per-row L2 normalize fp32 -> fp8 e4m3 into tiled layout;
// sq[row]=||n||^2; zero counter.
__global__ __launch_bounds__(256) void normalize_rows(
    const float* __restrict__ x, unsigned char* __restrict__ nf8,
    float* __restrict__ sq, unsigned int* __restrict__ counter)
{
    if (blockIdx.x == 0 && threadIdx.x == 0) { *counter = 0u; }
    int row = blockIdx.x * 4 + (threadIdx.x >> 6);
    int l = threadIdx.x & 63;
    const float4* xr = (const float4*)(x + (size_t)row * DDIM);
    float4 f0 = xr[l];
    float4 f1 = xr[l + 64];
    float s = f0.x*f0.x + f0.y*f0.y + f0.z*f0.z + f0.w*f0.w
            + f1.x*f1.x + f1.y*f1.y + f1.z*f1.z + f1.w*f1.w;
    #pragma unroll
    for (int m = 1; m < 64; m <<= 1) s += __shfl_xor(s, m);
    float rn = rsqrtf(s);
    int pk0 = __builtin_amdgcn_cvt_pk_fp8_f32(f0.x * rn, f0.y * rn, 0, false);
    pk0     = __builtin_amdgcn_cvt_pk_fp8_f32(f0.z * rn, f0.w * rn, pk0, true);
    int pk1 = __builtin_amdgcn_cvt_pk_fp8_f32(f1.x * rn, f1.y * rn, 0, false);
    pk1     = __builtin_amdgcn_cvt_pk_fp8_f32(f1.z * rn, f1.w * rn, pk1, true);
    // tiled scatter: pk0 covers k=[4l,4l+4), pk1 covers k=[4l+256,4l+260)
    size_t base = (size_t)(row >> 4) * 4 * 2048;
    int within = ((row & 15) + ((l >> 3) & 3) * 16) * 32 + (l & 7) * 4;
    int kc0 = l >> 5;          // k=4l       -> kc in {0,1}
    int kc1 = (l >> 5) + 2;    // k=4l+256   -> kc in {2,3}
    *(int*)(nf8 + base + (size_t)kc0 * 2048 + within) = pk0;
    *(int*)(nf8 + base + (size_t)kc1 * 2048 + within) = pk1;
    if (l == 0) sq[row] = s * rn * rn;
}

__device__ __forceinline__ void decode_tile(int u, int& ti, int& tj) {
    // u = tj*(tj+1)/2 + ti, ti <= tj
    int t = (int)((sqrtf(8.0f * (float)u + 1.0f) - 1.0f) * 0.5f);
    while ((t + 1) * (t + 2) / 2 <= u) ++t;
    while (t * (t + 1) / 2 > u) --t;
    tj = t;
    ti = u - t * (t + 1) / 2;
}

// Kernel 2: 128x128 block-tiles (4 waves x one 64x64 quadrant).
//  * A: LDS double-buffered (2 x 16 KB), 4 x 1 KB DMA per wave per chunk.
//  * B: REGISTER double-buffered, prefetched ONE CHUNK AHEAD (r6's in-path
//    B latency fixed; only 64 VGPRs of buffering -- the af-dbuf that made r7
//    spill is gone, af streams from LDS one frag at a time).
//  * Chunk-pair loop (even/odd static buffer naming, rule #20) -- 4 chunks
//    per tile, pipeline carried ACROSS tiles (next tile's chunk 0 staged +
//    bf-loaded during the last odd chunk).
//  * Counted vmcnt: at each chunk's wait point exactly 12 newer VMEM ops
//    (8 bf loads + 4 DMA) are outstanding; vmcnt(12) proves this chunk's
//    DMA + the current bf landed. All VMEM ops are fenced inside their
//    inter-barrier region by the "memory"-clobber asm barriers, so the
//    FIFO accounting is reorder-safe.
//  * GRID=512: every block resident at t=0, 4-5 tiles each.
__global__ __launch_bounds__(256, 2) void gram_hinge(
    const unsigned char* __restrict__ nf8, const float* __restrict__ sq,
    const int* __restrict__ y, double* __restrict__ part,
    unsigned int* __restrict__ counter, float* __restrict__ out)
{
    __shared__ unsigned char As[2][16384];   // 32 KB: A chunk frags, dbuf
    __shared__ float wpart[4];
    __shared__ double dpart[4];
    __shared__ int is_last;

    int tid = threadIdx.x;
    int w = tid >> 6, l = tid & 63;
    int wr = w >> 1, wc = w & 1;      // wave quadrant in 128x128 tile
    int lr = l & 15, q = l >> 4;

    // stage one chunk of A (8 frags = 16 KB) into dAb: 4 x 1 KB DMA per wave.
    auto stageA = [&](unsigned char* dAb, int pti, int pc) {
        #pragma unroll
        for (int i = 0; i < 4; ++i) {
            int t = w * 4 + i;
            int rf = t >> 1, half = t & 1;
            const unsigned char* src = nf8
                + ((size_t)((pti * 8 + rf) * 4 + pc)) * 2048 + half * 1024 + l * 16;
            __builtin_amdgcn_global_load_lds(
                (const __attribute__((address_space(1))) void*)src,
                (__attribute__((address_space(3))) void*)(dAb + t * 1024), 16, 0, 0);
        }
    };
    // load this wave's 4 B-frags for chunk pc (8 VMEM dwordx4 instrs)
    auto bload = [&](int ptj, int pc, i32x8* dst) {
        #pragma unroll
        for (int ni = 0; ni < 4; ++ni)
            dst[ni] = *(const i32x8*)(nf8
                + ((size_t)((ptj * 8 + wc * 4 + ni) * 4 + pc)) * 2048 + l * 32);
    };

    float acc0 = 0.f, acc1 = 0.f, acc2 = 0.f, acc3 = 0.f;

    int u = blockIdx.x;
    int ti, tj;
    decode_tile(u, ti, tj);

    i32x8 bfe[4], bfo[4];

    // pipeline prologue: tile-0 chunk-0 (A -> As[0], B -> even regs)
    bload(tj, 0, bfe);
    stageA(As[0], ti, 0);

    while (u < NUPPER) {
        int u_next = u + GRID;
        bool have_next = (u_next < NUPPER);
        int ti_n = 0, tj_n = 0;
        if (have_next) decode_tile(u_next, ti_n, tj_n);

        f32x4 accv[4][4] = {};

        #pragma unroll 1
        for (int cc = 0; cc < 2; ++cc) {
            // ===== even chunk e = 2cc (A in As[0], B in bfe) =====
            bload(tj, 2 * cc + 1, bfo);          // B for odd chunk, 1 ahead
            stageA(As[1], ti, 2 * cc + 1);       // A for odd chunk
            asm volatile("s_waitcnt vmcnt(12)" ::: "memory"); // dma(e)+bfe landed
            asm volatile("s_barrier" ::: "memory");
            __builtin_amdgcn_s_setprio(1);
            #pragma unroll
            for (int mi = 0; mi < 4; ++mi) {
                i32x8 af = *(const i32x8*)(As[0] + (wr * 4 + mi) * 2048 + l * 32);
                #pragma unroll
                for (int ni = 0; ni < 4; ++ni)
                    accv[mi][ni] = __builtin_amdgcn_mfma_scale_f32_16x16x128_f8f6f4(
                        af, bfe[ni], accv[mi][ni],
                        0, 0, 0, 0x7F7F7F7F, 0, 0x7F7F7F7F);
            }
            __builtin_amdgcn_s_setprio(0);
            asm volatile("s_barrier" ::: "memory");   // As[0] readers done

            // ===== odd chunk o = 2cc+1 (A in As[1], B in bfo) =====
            bool more = (cc == 0) || have_next;
            int nti = (cc == 0) ? ti : ti_n;
            int ntj = (cc == 0) ? tj : tj_n;
            int nc  = (cc == 0) ? 2 : 0;
            if (more) {
                bload(ntj, nc, bfe);             // B for next even chunk
                stageA(As[0], nti, nc);          // A for next even chunk
                asm volatile("s_waitcnt vmcnt(12)" ::: "memory"); // dma(o)+bfo landed
            } else {
                asm volatile("s_waitcnt vmcnt(0)" ::: "memory");  // end of work
            }
            asm volatile("s_barrier" ::: "memory");
            __builtin_amdgcn_s_setprio(1);
            #pragma unroll
            for (int mi = 0; mi < 4; ++mi) {
                i32x8 af = *(const i32x8*)(As[1] + (wr * 4 + mi) * 2048 + l * 32);
                #pragma unroll
                for (int ni = 0; ni < 4; ++ni)
                    accv[mi][ni] = __builtin_amdgcn_mfma_scale_f32_16x16x128_f8f6f4(
                        af, bfo[ni], accv[mi][ni],
                        0, 0, 0, 0x7F7F7F7F, 0, 0x7F7F7F7F);
            }
            __builtin_amdgcn_s_setprio(0);
            asm volatile("s_barrier" ::: "memory");   // As[1] readers done
        }

        // ---- per-tile epilogue (C/D layout: col=lane&15 -> j, row=q*4+reg -> i) ----
        // overlaps the already-issued next-tile chunk-0 DMA/bf loads
        {
            int jb = tj * 128 + wc * 64 + lr;
            float sqj[4]; int yj[4];
            #pragma unroll
            for (int ni = 0; ni < 4; ++ni) {
                sqj[ni] = sq[jb + ni * 16];
                yj[ni]  = y[jb + ni * 16];
            }
            bool skip = (ti == tj) && (wr > wc);        // strictly below diag
            bool full = (ti != tj) || (wc > wr);        // fully above diag
            if (!skip) {
                if (full) {
                    #pragma unroll
                    for (int mi = 0; mi < 4; ++mi) {
                        #pragma unroll
                        for (int r = 0; r < 4; ++r) {
                            int ia = ti * 128 + wr * 64 + mi * 16 + q * 4 + r;
                            float ci = THETA - sq[ia];
                            int yi = y[ia];
                            float h0 = fmaxf(fmaf(2.f, accv[mi][0][r], ci - sqj[0]), 0.f);
                            acc0 += (yi == yj[0]) ? h0 : -h0;
                            float h1 = fmaxf(fmaf(2.f, accv[mi][1][r], ci - sqj[1]), 0.f);
                            acc1 += (yi == yj[1]) ? h1 : -h1;
                            float h2 = fmaxf(fmaf(2.f, accv[mi][2][r], ci - sqj[2]), 0.f);
                            acc2 += (yi == yj[2]) ? h2 : -h2;
                            float h3 = fmaxf(fmaf(2.f, accv[mi][3][r], ci - sqj[3]), 0.f);
                            acc3 += (yi == yj[3]) ? h3 : -h3;
                        }
                    }
                } else {
                    // diagonal quadrant (wr==wc): count local col >= local row
                    #pragma unroll
                    for (int mi = 0; mi < 4; ++mi) {
                        #pragma unroll
                        for (int r = 0; r < 4; ++r) {
                            int rl_ = mi * 16 + q * 4 + r;
                            int ia = ti * 128 + wr * 64 + rl_;
                            float ci = THETA - sq[ia];
                            int yi = y[ia];
                            #pragma unroll
                            for (int ni = 0; ni < 4; ++ni) {
                                float h = fmaxf(fmaf(2.f, accv[mi][ni][r], ci - sqj[ni]), 0.f);
                                float sh = (yi == yj[ni]) ? h : -h;
                                if (ni * 16 + lr >= rl_) acc0 += sh;
                            }
                        }
                    }
                }
            }
        }

        u = u_next; ti = ti_n; tj = tj_n;
    }

    float local = (acc0 + acc1) + (acc2 + acc3);
    #pragma unroll
    for (int off = 32; off > 0; off >>= 1) local += __shfl_down(local, off);
    if (l == 0) wpart[w] = local;
    __syncthreads();
    if (tid == 0) {
        double ssum = (double)wpart[0] + (double)wpart[1]
                    + (double)wpart[2] + (double)wpart[3];
        __hip_atomic_store(&part[blockIdx.x], ssum, __ATOMIC_RELEASE, __HIP_MEMORY_SCOPE_AGENT);
        unsigned int ticket = __hip_atomic_fetch_add(
            counter, 1u, __ATOMIC_ACQ_REL, __HIP_MEMORY_SCOPE_AGENT);
        is_last = (ticket == GRID - 1) ? 1 : 0;
    }
    __syncthreads();
    if (is_last) {
        double s = 0.0;
        for (int i = tid; i < GRID; i += 256)
            s += __hip_atomic_load(&part[i], __ATOMIC_ACQUIRE, __HIP_MEMORY_SCOPE_AGENT);
        #pragma unroll
        for (int off = 32; off > 0; off >>= 1) s += __shfl_down(s, off);
        if (l == 0) dpart[w] = s;
        __syncthreads();
        if (tid == 0) {
            // add the analytically-known XI term: XI * #upper-tri pairs
            double total = (dpart[0] + dpart[1] + dpart[2] + dpart[3])
                         + (double)XI * NPAIRS_UP;
            const double m = 1.0 / ((double)BDIM * (double)BDIM - (double)BDIM);
            out[0] = (float)(total * m);
        }
    }
}

extern "C" void kernel_launch(void* const* d_in, const int* in_sizes, int n_in,
                              void* d_out, int out_size, void* d_ws, size_t ws_size,
                              hipStream_t stream) {
    const float* x = (const float*)d_in[0];
    const int* y = (const int*)d_in[1];
    float* out = (float*)d_out;

    unsigned char* nf8 = (unsigned char*)d_ws;                          // 4 MB fp8 (tiled)
    char* p = (char*)d_ws + (size_t)BDIM * DDIM;
    float* sq = (float*)p;                                              // 32 KB
    unsigned int* counter = (unsigned int*)(p + (size_t)BDIM * 4);
    double* part = (double*)(p + (size_t)BDIM * 4 + 64);                // GRID doubles

    normalize_rows<<<BDIM / 4, 256, 0, stream>>>(x, nf8, sq, counter);
    gram_hinge<<<GRID, 256, 0, stream>>>(nf8, sq, y, part, counter, out);
}